// Round 5
// baseline (243.692 us; speedup 1.0000x reference)
//
#include <hip/hip_runtime.h>
#include <math.h>

#define B_DIM 256
#define T_DIM 8192
#define BLOCK 256
#define GRID_BLOCKS 2048          // 8 blocks/CU * 4 waves = 32 waves/CU resident, one rotation
#define ITERS 4                   // 2048*256*4 = 2,097,152 rows
#define STRIDE (GRID_BLOCKS * BLOCK)

// ws layout: GRID_BLOCKS slots x 8 doubles (one slot per block, plain stores, no memset needed):
// 0 robot_sse, 1 nll_sum, 2 coher_sum, 3 coher_cnt, 4 pen2_sum, 5 velsq_sum, 6 accsq_sum

__global__ __launch_bounds__(BLOCK) void combined_loss_main(
    const float4* __restrict__ pred4,
    const float*  __restrict__ pred_phase,
    const float4* __restrict__ gt4,
    const int*    __restrict__ gt_phase,
    double* __restrict__ ws)
{
    __shared__ float s_red[4][8];

    const int tid = threadIdx.x;

    float sse = 0.0f, nll = 0.0f, csum = 0.0f, ccnt = 0.0f;
    float pen2 = 0.0f, velsq = 0.0f, accsq = 0.0f;

    for (int it = 0; it < ITERS; ++it) {
        const int r = (int)blockIdx.x * BLOCK + tid + it * STRIDE;  // flat row id
        const int t = r & (T_DIM - 1);
        const bool v1 = (t < T_DIM - 1);
        const bool v2 = (t < T_DIM - 2);

        const float4* pr = pred4 + (size_t)r * 3;
        const float4* gr = gt4   + (size_t)r * 3;
        const float*  pp = pred_phase + (size_t)r * 3;

        const int o1 = v1 ? 3 : 0;   // clamped offsets: always in-bounds
        const int o2 = v2 ? 6 : 0;

        float4 a0 = pr[0],  a1 = pr[1],      a2 = pr[2];        // row t
        float4 b0 = pr[o1], b1 = pr[o1 + 1], b2 = pr[o1 + 2];   // row t+1
        float4 c0 = pr[o2], c1 = pr[o2 + 1], c2 = pr[o2 + 2];   // row t+2
        float4 q0 = gr[0],  q1 = gr[1],      q2 = gr[2];

        const float l0 = pp[0],  l1 = pp[1],      l2 = pp[2];       // phase row t
        const float n0 = pp[o1], n1 = pp[o1 + 1], n2 = pp[o1 + 2];  // phase row t+1
        const int gidx = gt_phase[r];

        // ---- robot MSE ----
        {
            float d;
            d = a0.x - q0.x; sse += d*d;  d = a0.y - q0.y; sse += d*d;
            d = a0.z - q0.z; sse += d*d;  d = a0.w - q0.w; sse += d*d;
            d = a1.x - q1.x; sse += d*d;  d = a1.y - q1.y; sse += d*d;
            d = a1.z - q1.z; sse += d*d;  d = a1.w - q1.w; sse += d*d;
            d = a2.x - q2.x; sse += d*d;  d = a2.y - q2.y; sse += d*d;
            d = a2.z - q2.z; sse += d*d;  d = a2.w - q2.w; sse += d*d;
        }

        // ---- phase NLL (stable logsumexp over 3) ----
        {
            float m = fmaxf(l0, fmaxf(l1, l2));
            float lse = m + logf(expf(l0 - m) + expf(l1 - m) + expf(l2 - m));
            float sel = (gidx == 0) ? l0 : ((gidx == 1) ? l1 : l2);
            nll += lse - sel;
        }

        // ---- coherence (argmax at t vs t+1, both private) ----
        if (v1) {
            int p = 0; float pm = l0;
            if (l1 > pm) { pm = l1; p = 1; }
            if (l2 > pm) { pm = l2; p = 2; }
            int p1 = 0; float m1 = n0;
            if (n1 > m1) { m1 = n1; p1 = 1; }
            if (n2 > m1) { m1 = n2; p1 = 2; }
            int mask = (p == 0) ? 4 : ((p == 1) ? 1 : 3);  // illegal: (0,2),(1,0),(2,0),(2,1)
            if ((mask >> p1) & 1) { csum += m1 * m1; ccnt += 1.0f; }
        }

        // ---- stencil terms (register-private) ----
        {
            float rA[12] = { a0.x,a0.y,a0.z,a0.w, a1.x,a1.y,a1.z,a1.w, a2.x,a2.y,a2.z,a2.w };
            float rB[12] = { b0.x,b0.y,b0.z,b0.w, b1.x,b1.y,b1.z,b1.w, b2.x,b2.y,b2.z,b2.w };
            float rC[12] = { c0.x,c0.y,c0.z,c0.w, c1.x,c1.y,c1.z,c1.w, c2.x,c2.y,c2.z,c2.w };

            if (v1) {
                float vel[12];
                #pragma unroll
                for (int k = 0; k < 12; ++k) { vel[k] = rB[k] - rA[k]; velsq += vel[k]*vel[k]; }

                #pragma unroll
                for (int j = 0; j < 4; ++j) {
                    float sx = vel[3*j], sy = vel[3*j+1], sz = vel[3*j+2];
                    float sp = sqrtf(sx*sx + sy*sy + sz*sz);
                    float d = sp - 10.0f;
                    if (d > 0.0f) pen2 += d*d;
                }

                if (v2) {
                    #pragma unroll
                    for (int k = 0; k < 12; ++k) {
                        float a = rC[k] - 2.0f*rB[k] + rA[k];
                        accsq += a*a;
                    }
                }
            }
        }
    }

    // ---- wave shuffle reduce -> one barrier -> plain stores to private slot ----
    float vals[7] = { sse, nll, csum, ccnt, pen2, velsq, accsq };
    #pragma unroll
    for (int off = 32; off > 0; off >>= 1) {
        #pragma unroll
        for (int q = 0; q < 7; ++q)
            vals[q] += __shfl_down(vals[q], off, 64);
    }
    const int wave = tid >> 6, lane = tid & 63;
    if (lane == 0) {
        #pragma unroll
        for (int q = 0; q < 7; ++q) s_red[wave][q] = vals[q];
    }
    __syncthreads();
    if (tid < 7) {
        double acc = (double)s_red[0][tid] + (double)s_red[1][tid]
                   + (double)s_red[2][tid] + (double)s_red[3][tid];
        ws[(size_t)blockIdx.x * 8 + tid] = acc;   // unique slot: no atomic, no memset
    }
}

__global__ __launch_bounds__(256) void combined_loss_final(
    const double* __restrict__ ws, float* __restrict__ out)
{
    __shared__ double sred[4][7];
    const int tid = threadIdx.x;
    double v[7] = {0,0,0,0,0,0,0};
    #pragma unroll
    for (int s = 0; s < GRID_BLOCKS / 256; ++s) {
        const size_t slot = (size_t)(tid + s * 256) * 8;
        #pragma unroll
        for (int q = 0; q < 7; ++q) v[q] += ws[slot + q];
    }
    #pragma unroll
    for (int off = 32; off > 0; off >>= 1) {
        #pragma unroll
        for (int q = 0; q < 7; ++q)
            v[q] += __shfl_down(v[q], off, 64);
    }
    const int wave = tid >> 6, lane = tid & 63;
    if (lane == 0) {
        #pragma unroll
        for (int q = 0; q < 7; ++q) sred[wave][q] = v[q];
    }
    __syncthreads();
    if (tid == 0) {
        double s[7];
        #pragma unroll
        for (int q = 0; q < 7; ++q)
            s[q] = sred[0][q] + sred[1][q] + sred[2][q] + sred[3][q];
        const double robot = s[0] / (double)((size_t)B_DIM * T_DIM * 12);
        const double phase = s[1] / (double)((size_t)B_DIM * T_DIM);
        const double coher = (s[3] > 0.0) ? (s[2] / fmax(s[3], 1.0)) : 0.0;
        const double speed = 5.0  * (s[4] / (double)((size_t)B_DIM * (T_DIM - 1) * 4));
        const double vel   = 0.05 * (s[5] / (double)((size_t)B_DIM * (T_DIM - 1) * 12));
        const double acc   = 0.01 * (s[6] / (double)((size_t)B_DIM * (T_DIM - 2) * 12));
        out[0] = (float)(robot + phase + 10.0 * coher + speed + vel + acc);
    }
}

extern "C" void kernel_launch(void* const* d_in, const int* in_sizes, int n_in,
                              void* d_out, int out_size, void* d_ws, size_t ws_size,
                              hipStream_t stream)
{
    const float4* pred4      = (const float4*)d_in[0];
    const float*  pred_phase = (const float*)d_in[1];
    const float4* gt4        = (const float4*)d_in[2];
    const int*    gt_phase   = (const int*)d_in[3];
    double* ws  = (double*)d_ws;
    float*  out = (float*)d_out;

    combined_loss_main<<<dim3(GRID_BLOCKS), BLOCK, 0, stream>>>(pred4, pred_phase, gt4, gt_phase, ws);
    combined_loss_final<<<1, 256, 0, stream>>>(ws, out);
}

// Round 6
// 241.068 us; speedup vs baseline: 1.0109x; 1.0109x over previous
//
#include <hip/hip_runtime.h>
#include <math.h>

#define B_DIM 256
#define T_DIM 8192
#define BLOCK 256
#define ITERS 4
#define RB_BLOCKS 6144                       // robot: 6144*1024 f4 = 6,291,456 = B*T*3
#define PH_BLOCKS 1536                       // phase: 1536*1024 f4 = 1,572,864 = B*T*3/4
#define GRID_BLOCKS (RB_BLOCKS + PH_BLOCKS)
#define NSLOT 256
#define N4_ROBOT (B_DIM * T_DIM * 3)         // 6291456 float4s
#define N4_PHASE (B_DIM * T_DIM * 3 / 4)     // 1572864 float4s
#define BF4_ROBOT (T_DIM * 3)                // 24576 f4 per batch (24 blocks/batch)
#define BF4_PHASE (T_DIM * 3 / 4)            // 6144 f4 per batch (6 blocks/batch)

// ws: NSLOT slots x 8 doubles; 0 sse, 1 nll, 2 csum, 3 ccnt, 4 pen2, 5 velsq, 6 accsq

__global__ __launch_bounds__(BLOCK) void combined_loss_main(
    const float4* __restrict__ pred4,
    const float*  __restrict__ pred_phase,
    const float4* __restrict__ gt4,
    const int*    __restrict__ gt_phase,
    double* __restrict__ ws)
{
    __shared__ float s_red[4][8];
    const int tid = threadIdx.x;
    const int bx  = (int)blockIdx.x;

    float sse=0.f, nll=0.f, csum=0.f, ccnt=0.f, pen2=0.f, velsq=0.f, accsq=0.f;

    if (bx < RB_BLOCKS) {
        // ---------------- robot stream: flat float4, all loads unit-stride ----------------
        const int Jbase = bx * (BLOCK * ITERS);
        const int jbase = (bx % 24) * (BLOCK * ITERS);   // within-batch f4 offset
        #pragma unroll
        for (int it = 0; it < ITERS; ++it) {
            const int o = it * BLOCK + tid;
            const int J = Jbase + o;                     // global f4 index
            const int j = jbase + o;                     // within-batch f4 index

            float4 p0 = pred4[J];
            float4 g  = gt4[J];
            float4 p1 = pred4[min(J + 1, N4_ROBOT - 1)];
            float4 p3 = pred4[min(J + 3, N4_ROBOT - 1)];
            float4 p4 = pred4[min(J + 4, N4_ROBOT - 1)];
            float4 p6 = pred4[min(J + 6, N4_ROBOT - 1)];

            // sse (pointwise, flat-exact)
            float d;
            d = p0.x - g.x; sse += d*d;  d = p0.y - g.y; sse += d*d;
            d = p0.z - g.z; sse += d*d;  d = p0.w - g.w; sse += d*d;

            const bool vv = j < (BF4_ROBOT - 3);   // vel/speed valid
            const bool va = j < (BF4_ROBOT - 6);   // acc valid

            const float vx = p3.x - p0.x, vy = p3.y - p0.y;
            const float vz = p3.z - p0.z, vw = p3.w - p0.w;
            if (vv) velsq += vx*vx + vy*vy + vz*vz + vw*vw;

            if (va) {
                const float ax = p6.x - 2.f*p3.x + p0.x;
                const float ay = p6.y - 2.f*p3.y + p0.y;
                const float az = p6.z - 2.f*p3.z + p0.z;
                const float aw = p6.w - 2.f*p3.w + p0.w;
                accsq += ax*ax + ay*ay + az*az + aw*aw;
            }

            // speed: point ownership by j%3 (2/1/1 points), needs vel4(j) and vel4(j+1).xy
            const float wx = p4.x - p1.x, wy = p4.y - p1.y;
            const int s3 = j % 3;
            const float c0x = (s3 == 0) ? vx : ((s3 == 1) ? vz : vy);
            const float c0y = (s3 == 0) ? vy : ((s3 == 1) ? vw : vz);
            const float c0z = (s3 == 0) ? vz : ((s3 == 1) ? wx : vw);
            if (vv) {
                const float sp0 = sqrtf(c0x*c0x + c0y*c0y + c0z*c0z);
                const float d0 = sp0 - 10.f;
                if (d0 > 0.f) pen2 += d0*d0;
                if (s3 == 0) {
                    const float sp1 = sqrtf(vw*vw + wx*wx + wy*wy);
                    const float d1 = sp1 - 10.f;
                    if (d1 > 0.f) pen2 += d1*d1;
                }
            }
        }
    } else {
        // ---------------- phase stream: flat float4, 4 rows per 3 threads ----------------
        const int pb    = bx - RB_BLOCKS;
        const int batch = pb / 6;
        const int Mbase = pb * (BLOCK * ITERS);
        const int mbase = (pb % 6) * (BLOCK * ITERS);
        const int bT    = batch * T_DIM;
        const float4* ph4 = (const float4*)pred_phase;
        #pragma unroll
        for (int it = 0; it < ITERS; ++it) {
            const int o = it * BLOCK + tid;
            const int M = Mbase + o;
            const int m = mbase + o;

            float4 v  = ph4[M];
            float4 nv = ph4[min(M + 1, N4_PHASE - 1)];
            float4 nn = ph4[min(M + 2, N4_PHASE - 1)];

            const int q = m / 3;
            const int s = m - 3 * q;

            // Row A (every thread): logits la*, next-row logits na*
            const int   rA  = 4*q + ((s == 0) ? 0 : ((s == 1) ? 2 : 3));
            const float la0 = (s == 0) ? v.x  : ((s == 1) ? v.z  : v.y);
            const float la1 = (s == 0) ? v.y  : ((s == 1) ? v.w  : v.z);
            const float la2 = (s == 0) ? v.z  : ((s == 1) ? nv.x : v.w);
            const float na0 = (s == 0) ? v.w  : ((s == 1) ? nv.y : nv.x);
            const float na1 = (s == 0) ? nv.x : ((s == 1) ? nv.z : nv.y);
            const float na2 = (s == 0) ? nv.y : ((s == 1) ? nv.w : nv.z);

            const int gA = gt_phase[bT + rA];
            {
                const float mx  = fmaxf(la0, fmaxf(la1, la2));
                const float lse = mx + logf(expf(la0-mx) + expf(la1-mx) + expf(la2-mx));
                const float sl  = (gA == 0) ? la0 : ((gA == 1) ? la1 : la2);
                nll += lse - sl;
            }
            if (rA < T_DIM - 1) {
                int p = 0; float pm = la0;
                if (la1 > pm) { pm = la1; p = 1; }
                if (la2 > pm) { pm = la2; p = 2; }
                int p1 = 0; float m1 = na0;
                if (na1 > m1) { m1 = na1; p1 = 1; }
                if (na2 > m1) { m1 = na2; p1 = 2; }
                const int mask = (p == 0) ? 4 : ((p == 1) ? 1 : 3);
                if ((mask >> p1) & 1) { csum += m1*m1; ccnt += 1.f; }
            }

            // Row B (s==0 threads only): rB = 4q+1
            if (s == 0) {
                const int   rB  = 4*q + 1;
                const float lb0 = v.w,  lb1 = nv.x, lb2 = nv.y;
                const float nb0 = nv.z, nb1 = nv.w, nb2 = nn.x;
                const int gB = gt_phase[bT + rB];
                const float mx  = fmaxf(lb0, fmaxf(lb1, lb2));
                const float lse = mx + logf(expf(lb0-mx) + expf(lb1-mx) + expf(lb2-mx));
                const float sl  = (gB == 0) ? lb0 : ((gB == 1) ? lb1 : lb2);
                nll += lse - sl;
                int p = 0; float pm = lb0;
                if (lb1 > pm) { pm = lb1; p = 1; }
                if (lb2 > pm) { pm = lb2; p = 2; }
                int p1 = 0; float m1 = nb0;
                if (nb1 > m1) { m1 = nb1; p1 = 1; }
                if (nb2 > m1) { m1 = nb2; p1 = 2; }
                const int mask = (p == 0) ? 4 : ((p == 1) ? 1 : 3);
                if ((mask >> p1) & 1) { csum += m1*m1; ccnt += 1.f; }
            }
        }
    }

    // ---- wave shuffle reduce -> one barrier -> slotted fp64 atomics ----
    float vals[7] = { sse, nll, csum, ccnt, pen2, velsq, accsq };
    #pragma unroll
    for (int off = 32; off > 0; off >>= 1) {
        #pragma unroll
        for (int q = 0; q < 7; ++q)
            vals[q] += __shfl_down(vals[q], off, 64);
    }
    const int wave = tid >> 6, lane = tid & 63;
    if (lane == 0) {
        #pragma unroll
        for (int q = 0; q < 7; ++q) s_red[wave][q] = vals[q];
    }
    __syncthreads();
    if (tid < 7) {
        double acc = (double)s_red[0][tid] + (double)s_red[1][tid]
                   + (double)s_red[2][tid] + (double)s_red[3][tid];
        atomicAdd(&ws[(size_t)(bx & (NSLOT - 1)) * 8 + tid], acc);
    }
}

__global__ __launch_bounds__(256) void combined_loss_final(
    const double* __restrict__ ws, float* __restrict__ out)
{
    __shared__ double sred[4][7];
    const int tid = threadIdx.x;
    double v[7];
    #pragma unroll
    for (int q = 0; q < 7; ++q) v[q] = ws[(size_t)tid * 8 + q];
    #pragma unroll
    for (int off = 32; off > 0; off >>= 1) {
        #pragma unroll
        for (int q = 0; q < 7; ++q)
            v[q] += __shfl_down(v[q], off, 64);
    }
    const int wave = tid >> 6, lane = tid & 63;
    if (lane == 0) {
        #pragma unroll
        for (int q = 0; q < 7; ++q) sred[wave][q] = v[q];
    }
    __syncthreads();
    if (tid == 0) {
        double s[7];
        #pragma unroll
        for (int q = 0; q < 7; ++q)
            s[q] = sred[0][q] + sred[1][q] + sred[2][q] + sred[3][q];
        const double robot = s[0] / (double)((size_t)B_DIM * T_DIM * 12);
        const double phase = s[1] / (double)((size_t)B_DIM * T_DIM);
        const double coher = (s[3] > 0.0) ? (s[2] / fmax(s[3], 1.0)) : 0.0;
        const double speed = 5.0  * (s[4] / (double)((size_t)B_DIM * (T_DIM - 1) * 4));
        const double vel   = 0.05 * (s[5] / (double)((size_t)B_DIM * (T_DIM - 1) * 12));
        const double acc   = 0.01 * (s[6] / (double)((size_t)B_DIM * (T_DIM - 2) * 12));
        out[0] = (float)(robot + phase + 10.0 * coher + speed + vel + acc);
    }
}

extern "C" void kernel_launch(void* const* d_in, const int* in_sizes, int n_in,
                              void* d_out, int out_size, void* d_ws, size_t ws_size,
                              hipStream_t stream)
{
    const float4* pred4      = (const float4*)d_in[0];
    const float*  pred_phase = (const float*)d_in[1];
    const float4* gt4        = (const float4*)d_in[2];
    const int*    gt_phase   = (const int*)d_in[3];
    double* ws  = (double*)d_ws;
    float*  out = (float*)d_out;

    hipMemsetAsync(d_ws, 0, (size_t)NSLOT * 8 * sizeof(double), stream);

    combined_loss_main<<<dim3(GRID_BLOCKS), BLOCK, 0, stream>>>(pred4, pred_phase, gt4, gt_phase, ws);
    combined_loss_final<<<1, 256, 0, stream>>>(ws, out);
}